// Round 13
// baseline (95.804 us; speedup 1.0000x reference)
//
#include <hip/hip_runtime.h>

// LSHAttention: reference returns ONLY sticker = argsort(buckets) [B,S] int32.
// B=4, S=4096, D=1024, NR=32, 64 buckets.
//
// k1: grid 512 = (b:4, c32:128 -> 32 tokens), 256 thr = 4 waves, full K.
//   *** 2 blocks/CU = 2 waves/SIMD (the round-12 fix: R12 was identical in
//   instruction counts but ran 1 wave/SIMD and was latency-dead at 28% LDS
//   pipe utilization). ***
//   Wave = 8 tokens; lane = (r_t:4 -> 8 r, kl:16 -> 4 k per 64-k tile).
//   acc = 8 tok x 8 r = 64 f32 (~130 VGPR; waves_per_eu(2,2) -> 256 cap).
//   R staged in QUARTERS (32 KB) shared by the block; Q streams through
//   wave-private double buffers (2 KB each) via global_load_lds, 2 tiles in
//   flight (per-wave vmcnt(2)), NO barriers inside quarters.
//   Layouts (staged via pre-swizzled DMA source, T21):
//     Q buf [8 tok][16 f4] linear; read addr = j*16 + kl -> 2-way (free).
//     R qtr slot = khi*64 + klow*8 + (r2 ^ (khi&7)) -> read spreads all 8
//     f4-groups; staging source = row-perm within 512B, coalesced.
//   Per tile/thread: 8 qv + 8 rv b128, 256 FMA (ratio 16).
//   Epilogue: shfl_xor(1,2,4,8) kl-reduce, xs dump, argmax + hist in-block.
// k2/k3: 32-token-chunk scan + stable scatter (verified rounds 7-12 verbatim).

#define B_DIM 4
#define S_LEN 4096
#define D_DIM 1024
#define NRR 32
#define NBK 64
#define TMK 32                  // tokens per block = hist chunk
#define NC32 (S_LEN / TMK)      // 128 chunks
#define QOFF 2048               // f4 offset of Q region (R quarter = 2048 f4)

typedef const __attribute__((address_space(1))) void* gas_t;
typedef __attribute__((address_space(3))) void* las_t;

__global__ void __launch_bounds__(256) __attribute__((amdgpu_waves_per_eu(2, 2)))
k1_buckets(const float* __restrict__ Q, const float* __restrict__ R,
           int* __restrict__ buckets, int* __restrict__ hist)
{
    __shared__ float4 smem4[QOFF + 1024];   // R quarter 32KB + 4w x 2buf x 2KB
    __shared__ float xs[TMK * 36];          // [tok][r] stride 36 (f4-aligned)
    __shared__ int cnt[NBK];

    const int t = threadIdx.x;
    const int b = blockIdx.x >> 7;
    const int c32 = blockIdx.x & 127;

    const int w = t >> 6;
    const int lane = t & 63;
    const int r_t = lane >> 4;          // 4 groups x 8 r
    const int kl = lane & 15;           // 16-way k split (4 k per tile)

    const float4* Qw4 = (const float4*)(Q + ((size_t)b * S_LEN + c32 * TMK + w * 8) * D_DIM);
    const float4* Rg4 = (const float4*)(R + (size_t)b * D_DIM * NRR);

    // hot-loop constant indices
    const int qwoff = QOFF + w * 256;                   // + buf*128 + j*16 + kl
    const int rbase = (kl >> 1) * 64 + (kl & 1) * 32;   // + tl*512 + c*8 + rx
    const int rx0 = (r_t * 2 + 0) ^ (kl >> 1);
    const int rx1 = (r_t * 2 + 1) ^ (kl >> 1);

#define STAGE_R(QTR)                                                          \
    {                                                                         \
        _Pragma("unroll")                                                     \
        for (int i = 0; i < 8; ++i) {                                         \
            __builtin_amdgcn_global_load_lds(                                 \
                (gas_t)(Rg4 + ((size_t)(QTR) * 256 + (w * 8 + i) * 8          \
                               + (lane >> 3)) * 8 + ((lane & 7) ^ i)),        \
                (las_t)&smem4[w * 512 + i * 64 + lane], 16, 0, 0);            \
        }                                                                     \
    }

#define ISSUE_Q(TAU, BUF)                                                     \
    {                                                                         \
        _Pragma("unroll")                                                     \
        for (int i = 0; i < 2; ++i) {                                         \
            const int s = i * 64 + lane;                                      \
            __builtin_amdgcn_global_load_lds(                                 \
                (gas_t)(Qw4 + (size_t)(s >> 4) * 256 + (TAU) * 16 + (s & 15)),\
                (las_t)&smem4[qwoff + (BUF) * 128 + s], 16, 0, 0);            \
        }                                                                     \
    }

#define COMPUTE(TL, BUF)                                                      \
    {                                                                         \
        const float4* rb = smem4 + (TL) * 512 + rbase;                        \
        const float4* qb = smem4 + qwoff + (BUF) * 128 + kl;                  \
        float4 rv[4][2];                                                      \
        _Pragma("unroll")                                                     \
        for (int c = 0; c < 4; ++c) {                                         \
            rv[c][0] = rb[c * 8 + rx0];                                       \
            rv[c][1] = rb[c * 8 + rx1];                                       \
        }                                                                     \
        _Pragma("unroll")                                                     \
        for (int j = 0; j < 8; ++j) {                                         \
            const float4 qv = qb[j * 16];                                     \
            _Pragma("unroll")                                                 \
            for (int c = 0; c < 4; ++c) {                                     \
                const float s = c == 0 ? qv.x : c == 1 ? qv.y                 \
                              : c == 2 ? qv.z : qv.w;                         \
                _Pragma("unroll")                                             \
                for (int p = 0; p < 2; ++p) {                                 \
                    acc[j][p].x = fmaf(s, rv[c][p].x, acc[j][p].x);           \
                    acc[j][p].y = fmaf(s, rv[c][p].y, acc[j][p].y);           \
                    acc[j][p].z = fmaf(s, rv[c][p].z, acc[j][p].z);           \
                    acc[j][p].w = fmaf(s, rv[c][p].w, acc[j][p].w);           \
                }                                                             \
            }                                                                 \
        }                                                                     \
    }

    float4 acc[8][2];
#pragma unroll
    for (int j = 0; j < 8; ++j) {
        acc[j][0] = make_float4(0.f, 0.f, 0.f, 0.f);
        acc[j][1] = make_float4(0.f, 0.f, 0.f, 0.f);
    }
    if (t < NBK) cnt[t] = 0;

    // prologue: R quarter 0 + first two Q tiles, full drain, one barrier
    STAGE_R(0)
    ISSUE_Q(0, 0)
    ISSUE_Q(1, 1)
    asm volatile("s_waitcnt vmcnt(0)" ::: "memory");
    __syncthreads();

    int tau = 0;
    for (int qtr = 0; qtr < 4; ++qtr) {
        if (qtr) {
            __syncthreads();            // everyone done reading old R quarter
            STAGE_R(qtr)
            asm volatile("s_waitcnt vmcnt(0)" ::: "memory");
            __syncthreads();            // new R quarter visible to all
        }
#pragma unroll
        for (int tl = 0; tl < 4; ++tl, ++tau) {
            // wait my tile's 2 DMAs (leaves next tile's 2 in flight)
            asm volatile("s_waitcnt vmcnt(2)" ::: "memory");
            COMPUTE(tl, tau & 1)
            // all my ds_reads of this buffer returned before DMA overwrites it
            asm volatile("s_waitcnt lgkmcnt(0)" ::: "memory");
            if (tau + 2 < 16) ISSUE_Q(tau + 2, tau & 1)
        }
    }
#undef STAGE_R
#undef ISSUE_Q
#undef COMPUTE

    // ---- butterfly reduce over kl (lane bits 0-3) ----
#pragma unroll
    for (int j = 0; j < 8; ++j)
#pragma unroll
        for (int p = 0; p < 2; ++p)
#pragma unroll
            for (int off = 1; off < 16; off <<= 1) {
                acc[j][p].x += __shfl_xor(acc[j][p].x, off, 64);
                acc[j][p].y += __shfl_xor(acc[j][p].y, off, 64);
                acc[j][p].z += __shfl_xor(acc[j][p].z, off, 64);
                acc[j][p].w += __shfl_xor(acc[j][p].w, off, 64);
            }

    __syncthreads();                    // all LDS reads done; safe to reuse xs
    if (kl == 0) {                      // lanes 0,16,32,48 per wave
        float4* xsf4 = (float4*)xs;
#pragma unroll
        for (int j = 0; j < 8; ++j) {
            xsf4[(w * 8 + j) * 9 + r_t * 2 + 0] = acc[j][0];
            xsf4[(w * 8 + j) * 9 + r_t * 2 + 1] = acc[j][1];
        }
    }
    __syncthreads();

    if (t < TMK) {
        // argmax(concat[xR,-xR]) with first-occurrence tie-break
        float m1 = xs[t * 36 + 0]; int i1 = 0;
        float m2 = m1;             int i2 = 0;
#pragma unroll
        for (int r = 1; r < NRR; ++r) {
            const float v = xs[t * 36 + r];
            if (v > m1) { m1 = v; i1 = r; }
            if (v < m2) { m2 = v; i2 = r; }
        }
        const int bk = (m1 >= -m2) ? i1 : (NRR + i2);
        buckets[(size_t)b * S_LEN + c32 * TMK + t] = bk;
        atomicAdd(&cnt[bk], 1);
    }
    __syncthreads();
    if (t < NBK) hist[((size_t)b * NC32 + c32) * NBK + t] = cnt[t];
}

// One block, 256 threads: thread = (batch b = t/64, bucket bk = t%64).
__global__ __launch_bounds__(256) void k2_scan(
    const int* __restrict__ hist, int* __restrict__ chunkOffset)
{
    const int t = threadIdx.x;
    const int b = t >> 6;
    const int bk = t & 63;
    const int lane = t & 63;

    int total = 0;
    for (int c = 0; c < NC32; ++c)
        total += hist[((size_t)b * NC32 + c) * NBK + bk];

    int incl = total;
#pragma unroll
    for (int off = 1; off < 64; off <<= 1) {
        int n = __shfl_up(incl, off, 64);
        if (lane >= off) incl += n;
    }
    int run = incl - total;   // exclusive prefix over buckets = bucketStart

    for (int c = 0; c < NC32; ++c) {
        int h = hist[((size_t)b * NC32 + c) * NBK + bk];
        chunkOffset[((size_t)b * NC32 + c) * NBK + bk] = run;
        run += h;
    }
}

// Stable scatter: 32-token chunks; rank via ballot restricted to own 32-lane half.
__global__ __launch_bounds__(256) void k3_scatter(
    const int* __restrict__ buckets, const int* __restrict__ chunkOffset,
    int* __restrict__ out)
{
    const int gid = blockIdx.x * 256 + threadIdx.x;  // 0..16383
    const int b = gid >> 12;
    const int s = gid & (S_LEN - 1);
    const int chunk = s >> 5;                        // 32-token chunk
    const int lane = threadIdx.x & 63;

    const int bk = buckets[gid];

    unsigned long long m = ~0ull;
#pragma unroll
    for (int i = 0; i < 6; ++i) {
        unsigned long long bi = __ballot((bk >> i) & 1);
        m &= ((bk >> i) & 1) ? bi : ~bi;
    }
    const unsigned int m32 = (unsigned int)(m >> (lane & 32));
    const int rank = __popc(m32 & ((1u << (lane & 31)) - 1u));

    const int pos = chunkOffset[((size_t)b * NC32 + chunk) * NBK + bk] + rank;
    out[(size_t)b * S_LEN + pos] = s;
}

extern "C" void kernel_launch(void* const* d_in, const int* in_sizes, int n_in,
                              void* d_out, int out_size, void* d_ws, size_t ws_size,
                              hipStream_t stream) {
    const float* Q = (const float*)d_in[0];
    // d_in[1] = key, d_in[2] = value: dead code in the reference, never read.
    const float* R = (const float*)d_in[3];

    int* buckets     = (int*)d_ws;                      // 16384 ints
    int* hist        = buckets + B_DIM * S_LEN;         // 4*128*64 = 32768 ints
    int* chunkOffset = hist + B_DIM * NC32 * NBK;       // 32768 ints

    k1_buckets<<<B_DIM * NC32, 256, 0, stream>>>(Q, R, buckets, hist);
    k2_scan   <<<1,            256, 0, stream>>>(hist, chunkOffset);
    k3_scatter<<<(B_DIM * S_LEN) / 256, 256, 0, stream>>>(buckets, chunkOffset, (int*)d_out);
}

// Round 14
// 64.211 us; speedup vs baseline: 1.4920x; 1.4920x over previous
//
#include <hip/hip_runtime.h>

// LSHAttention: reference returns ONLY sticker = argsort(buckets) [B,S] int32.
// B=4, S=4096, D=1024, NR=32, 64 buckets.
//
// ROUND 14 = ROUND 11 VERBATIM + pipeline depth 1 -> 2 (the single change).
// R11 measured: k1 40 us, VGPR 84, NO spill, but every wave stalled on vmcnt
// each tile (6 loads only 1 tile ahead < 900-cyc HBM latency) and 2 barriers/
// tile convoyed the stalls. Fix: TRIPLE-buffered 128-k tiles (Q 8KB + R 16KB
// per buffer, 76 KB LDS total, 2 blocks/CU as before), tau-loop fully
// unrolled so buffer indices are literals; per-wave counted vmcnt(12)
// (= tiles tau+1, tau+2 in flight) in steady state, 6/0 only at the tail.
//
// k1: grid 1024 = (b:4, ch:256 -> 16 tokens), 256 thr = 4 waves, full K.
//   Thread = (tok_t:2 x8tok, r_t:4 x8r, kl:8); kq = w*8+kl covers 128k/tile.
//   acc = 8tok x 8r = 64 f32; waves_per_eu(4,4) (replicates R11's 84-VGPR
//   no-spill allocation).
//   Q LDS [16tok][32 f4] natural (read 8 grp x 2-way = free);
//   R LDS slot = k*8 + (rq ^ ((k>>2)&7)) via pre-swizzled DMA source.
//   Epilogue: shfl_xor(1,2,4) kl-reduce, 4-slice LDS sum, argmax, 16-tok hist.
// k2: offset scan (256 chunks); k3: stable scatter (verified rounds 11-13).

#define B_DIM 4
#define S_LEN 4096
#define D_DIM 1024
#define NRR 32
#define NBK 64
#define TMK 16                  // tokens per block = hist chunk
#define NCH (S_LEN / TMK)       // 256 chunks
#define NT 8                    // K-tiles of 128
#define ROFF 1536               // f4 offset of R buffers (3 Q buffers first)

typedef const __attribute__((address_space(1))) void* gas_t;
typedef __attribute__((address_space(3))) void* las_t;

__global__ void __launch_bounds__(256) __attribute__((amdgpu_waves_per_eu(4, 4)))
k1_buckets(const float* __restrict__ Q, const float* __restrict__ R,
           int* __restrict__ buckets, int* __restrict__ hist)
{
    __shared__ float4 smem4[ROFF + 3072];  // 3x Q(512 f4) + 3x R(1024 f4) = 72KB
    __shared__ float xs[TMK * 33];
    __shared__ int cnt[NBK];

    const int t = threadIdx.x;
    const int b = blockIdx.x >> 8;
    const int ch = blockIdx.x & 255;

    const int w = t >> 6;
    const int lane = t & 63;
    const int tok_t = lane >> 5;        // 2 groups x 8 tokens
    const int r_t = (lane >> 3) & 3;    // 4 groups x 8 r (2 f4)
    const int kl = lane & 7;            // 8-way k split in wave
    const int kq = w * 8 + kl;          // k-quad within tile [0,32)
    const int dwb = t & ~63;            // wave-uniform DMA dest base (f4)
    const int rsw0 = (r_t * 2 + 0) ^ kl;
    const int rsw1 = (r_t * 2 + 1) ^ kl;
    const int qoff = tok_t * 256 + kq;  // + j*32
    const int roff = kq * 32;           // + kk*8 + rsw

    const float4* Qg4 = (const float4*)(Q + ((size_t)b * S_LEN + ch * TMK) * D_DIM);
    const float4* Rg4 = (const float4*)(R + (size_t)b * D_DIM * NRR);

#define ISSUE(TILE, D)                                                        \
    {                                                                         \
        _Pragma("unroll")                                                     \
        for (int i = 0; i < 2; ++i) {                                         \
            const int f = t + 256 * i;                                        \
            __builtin_amdgcn_global_load_lds(                                 \
                (gas_t)(Qg4 + (size_t)(f >> 5) * 256 + (TILE) * 32 + (f & 31)),\
                (las_t)&smem4[(D) * 512 + (i << 8) + dwb], 16, 0, 0);         \
        }                                                                     \
        _Pragma("unroll")                                                     \
        for (int i = 0; i < 4; ++i) {                                         \
            const int f = t + 256 * i;                                        \
            __builtin_amdgcn_global_load_lds(                                 \
                (gas_t)(Rg4 + ((size_t)(TILE) * 128 + (f >> 3)) * 8           \
                        + ((f & 7) ^ ((f >> 5) & 7))),                        \
                (las_t)&smem4[ROFF + (D) * 1024 + (i << 8) + dwb], 16, 0, 0); \
        }                                                                     \
    }

#define COMPUTE(D)                                                            \
    {                                                                         \
        const float4* qb = smem4 + (D) * 512;                                 \
        const float4* rb = smem4 + ROFF + (D) * 1024;                         \
        float4 rv[4][2];                                                      \
        _Pragma("unroll")                                                     \
        for (int kk = 0; kk < 4; ++kk) {                                      \
            rv[kk][0] = rb[roff + kk * 8 + rsw0];                             \
            rv[kk][1] = rb[roff + kk * 8 + rsw1];                             \
        }                                                                     \
        _Pragma("unroll")                                                     \
        for (int j = 0; j < 8; ++j) {                                         \
            const float4 qv = qb[qoff + j * 32];                              \
            _Pragma("unroll")                                                 \
            for (int kk = 0; kk < 4; ++kk) {                                  \
                const float s = kk == 0 ? qv.x : kk == 1 ? qv.y               \
                              : kk == 2 ? qv.z : qv.w;                        \
                _Pragma("unroll")                                             \
                for (int p = 0; p < 2; ++p) {                                 \
                    acc[j][p].x = fmaf(s, rv[kk][p].x, acc[j][p].x);          \
                    acc[j][p].y = fmaf(s, rv[kk][p].y, acc[j][p].y);          \
                    acc[j][p].z = fmaf(s, rv[kk][p].z, acc[j][p].z);          \
                    acc[j][p].w = fmaf(s, rv[kk][p].w, acc[j][p].w);          \
                }                                                             \
            }                                                                 \
        }                                                                     \
    }

    float4 acc[8][2];
#pragma unroll
    for (int j = 0; j < 8; ++j) {
        acc[j][0] = make_float4(0.f, 0.f, 0.f, 0.f);
        acc[j][1] = make_float4(0.f, 0.f, 0.f, 0.f);
    }

    ISSUE(0, 0)
    ISSUE(1, 1)
#pragma unroll
    for (int tau = 0; tau < NT; ++tau) {
        if (tau + 2 < NT) {
            ISSUE(tau + 2, (tau + 2) % 3)
            // tiles tau+1, tau+2 (12 loads) stay in flight; tile tau landed
            asm volatile("s_waitcnt vmcnt(12)\n\ts_barrier" ::: "memory");
        } else if (tau + 1 < NT) {
            asm volatile("s_waitcnt vmcnt(6)\n\ts_barrier" ::: "memory");
        } else {
            asm volatile("s_waitcnt vmcnt(0)\n\ts_barrier" ::: "memory");
        }
        COMPUTE(tau % 3)
        // all my LDS reads of this buffer done before iter tau+1 overwrites it
        asm volatile("s_waitcnt lgkmcnt(0)\n\ts_barrier" ::: "memory");
    }
#undef ISSUE
#undef COMPUTE

    // ---- reduce over kl (lane bits 0-2): lanes kl==0 hold wave partial ----
#pragma unroll
    for (int j = 0; j < 8; ++j)
#pragma unroll
        for (int p = 0; p < 2; ++p) {
#pragma unroll
            for (int off = 1; off < 8; off <<= 1) {
                acc[j][p].x += __shfl_xor(acc[j][p].x, off, 64);
                acc[j][p].y += __shfl_xor(acc[j][p].y, off, 64);
                acc[j][p].z += __shfl_xor(acc[j][p].z, off, 64);
                acc[j][p].w += __shfl_xor(acc[j][p].w, off, 64);
            }
        }

    if (t < NBK) cnt[t] = 0;
    // ---- dump 4 wave-slices [16 tok][8 rq f4] into smem4[0,512) ----
    if (kl == 0) {
#pragma unroll
        for (int j = 0; j < 8; ++j) {
            const int tok = tok_t * 8 + j;
            smem4[w * 128 + tok * 8 + r_t * 2 + 0] = acc[j][0];
            smem4[w * 128 + tok * 8 + r_t * 2 + 1] = acc[j][1];
        }
    }
    __syncthreads();

    // ---- sum 4 slices (128 f4 positions) ----
    if (t < 128) {
        float4 s = smem4[t];
#pragma unroll
        for (int ww = 1; ww < 4; ++ww) {
            const float4 v = smem4[ww * 128 + t];
            s.x += v.x; s.y += v.y; s.z += v.z; s.w += v.w;
        }
        const int tok = t >> 3, rq = t & 7;
        xs[tok * 33 + rq * 4 + 0] = s.x;
        xs[tok * 33 + rq * 4 + 1] = s.y;
        xs[tok * 33 + rq * 4 + 2] = s.z;
        xs[tok * 33 + rq * 4 + 3] = s.w;
    }
    __syncthreads();

    if (t < TMK) {
        // argmax(concat[xR,-xR]) with first-occurrence tie-break
        float m1 = xs[t * 33 + 0]; int i1 = 0;
        float m2 = m1;             int i2 = 0;
#pragma unroll
        for (int r = 1; r < NRR; ++r) {
            const float v = xs[t * 33 + r];
            if (v > m1) { m1 = v; i1 = r; }
            if (v < m2) { m2 = v; i2 = r; }
        }
        const int bk = (m1 >= -m2) ? i1 : (NRR + i2);
        buckets[(size_t)b * S_LEN + ch * TMK + t] = bk;
        atomicAdd(&cnt[bk], 1);
    }
    __syncthreads();
    if (t < NBK) hist[((size_t)b * NCH + ch) * NBK + t] = cnt[t];
}

// One block, 256 threads: thread = (batch b = t/64, bucket bk = t%64).
__global__ __launch_bounds__(256) void k2_scan(
    const int* __restrict__ hist, int* __restrict__ chunkOffset)
{
    const int t = threadIdx.x;
    const int b = t >> 6;
    const int bk = t & 63;
    const int lane = t & 63;

    int total = 0;
    for (int c = 0; c < NCH; ++c)
        total += hist[((size_t)b * NCH + c) * NBK + bk];

    int incl = total;
#pragma unroll
    for (int off = 1; off < 64; off <<= 1) {
        int n = __shfl_up(incl, off, 64);
        if (lane >= off) incl += n;
    }
    int run = incl - total;   // exclusive prefix over buckets = bucketStart

    for (int c = 0; c < NCH; ++c) {
        int h = hist[((size_t)b * NCH + c) * NBK + bk];
        chunkOffset[((size_t)b * NCH + c) * NBK + bk] = run;
        run += h;
    }
}

// Stable scatter: 16-token chunks; rank via ballot within own 16-lane subgroup.
__global__ __launch_bounds__(256) void k3_scatter(
    const int* __restrict__ buckets, const int* __restrict__ chunkOffset,
    int* __restrict__ out)
{
    const int gid = blockIdx.x * 256 + threadIdx.x;  // 0..16383
    const int b = gid >> 12;
    const int s = gid & (S_LEN - 1);
    const int chunk = s >> 4;                        // 16-token chunk
    const int lane = threadIdx.x & 63;

    const int bk = buckets[gid];

    unsigned long long m = ~0ull;
#pragma unroll
    for (int i = 0; i < 6; ++i) {
        unsigned long long bi = __ballot((bk >> i) & 1);
        m &= ((bk >> i) & 1) ? bi : ~bi;
    }
    const unsigned int m16 = (unsigned int)((m >> (lane & 48)) & 0xFFFFull);
    const int rank = __popc(m16 & ((1u << (lane & 15)) - 1u));

    const int pos = chunkOffset[((size_t)b * NCH + chunk) * NBK + bk] + rank;
    out[(size_t)b * S_LEN + pos] = s;
}

extern "C" void kernel_launch(void* const* d_in, const int* in_sizes, int n_in,
                              void* d_out, int out_size, void* d_ws, size_t ws_size,
                              hipStream_t stream) {
    const float* Q = (const float*)d_in[0];
    // d_in[1] = key, d_in[2] = value: dead code in the reference, never read.
    const float* R = (const float*)d_in[3];

    int* buckets     = (int*)d_ws;                      // 16384 ints
    int* hist        = buckets + B_DIM * S_LEN;         // 4*256*64 = 65536 ints
    int* chunkOffset = hist + B_DIM * NCH * NBK;        // 65536 ints

    k1_buckets<<<B_DIM * NCH, 256, 0, stream>>>(Q, R, buckets, hist);
    k2_scan   <<<1,           256, 0, stream>>>(hist, chunkOffset);
    k3_scatter<<<(B_DIM * S_LEN) / 256, 256, 0, stream>>>(buckets, chunkOffset, (int*)d_out);
}

// Round 15
// 46.828 us; speedup vs baseline: 2.0459x; 1.3712x over previous
//
#include <hip/hip_runtime.h>

// LSHAttention: reference returns ONLY sticker = argsort(buckets) [B,S] int32.
// B=4, S=4096, D=1024, NR=32, 64 buckets.
//
// ROUND 15 = ROUND 11's verified hot loop, scaled for RESIDENCY:
//   512-thr blocks (8 waves) x 32 tokens, 68.6 KB LDS -> 2 blocks/CU
//   GUARANTEED = 16 waves/CU = 4 waves/SIMD (R11/R12/R14 ran at <=8 waves/CU
//   and were latency-dead; VALU ~8us + LDS ~12us say the work fits in ~20us
//   once latency is hidden).
// k1: grid 512 = (b:4, c32:128 -> 32 tokens) = 2 blocks/CU exactly.
//   Wave w = (wt:2 token-half, wk:4 k-quarter); thread = (tok_t:2, r_t:4, kl:8);
//   kq = wk*8+kl covers 128k/tile; acc = 8tok x 8r = 64 f32 (R11's 84-VGPR
//   no-spill footprint; waves_per_eu(4,4)).
//   K-tiles of 128, double-buffered, global_load_lds width-16 staging:
//     Q LDS [32tok][32 f4] natural; hot read 8 grp x 2-way broadcast = free.
//     R LDS slot = k*8 + (rq ^ ((k>>2)&7)) via pre-swizzled DMA source.
//   Schedule: ISSUE(t+1); vmcnt(4)+barrier; COMPUTE; lgkmcnt(0)+barrier.
//   Epilogue: shfl_xor(1,2,4) kl-reduce, 4 wk-slices LDS sum, argmax, hist.
// k2: offset scan (128 chunks); k3: stable scatter 32-tok (verified R7-R13).

#define B_DIM 4
#define S_LEN 4096
#define D_DIM 1024
#define NRR 32
#define NBK 64
#define TMK 32                  // tokens per block = hist chunk
#define NC32 (S_LEN / TMK)      // 128 chunks
#define NT 8                    // K-tiles of 128

typedef const __attribute__((address_space(1))) void* gas_t;
typedef __attribute__((address_space(3))) void* las_t;

__global__ void __launch_bounds__(512) __attribute__((amdgpu_waves_per_eu(4, 4)))
k1_buckets(const float* __restrict__ Q, const float* __restrict__ R,
           int* __restrict__ buckets, int* __restrict__ hist)
{
    __shared__ float4 smem4[4096];  // Q0[0,1024) Q1[1024,2048) R0[2048,3072) R1[3072,4096)
    __shared__ float xs[TMK * 33];
    __shared__ int cnt[NBK];

    const int t = threadIdx.x;
    const int b = blockIdx.x >> 7;
    const int c32 = blockIdx.x & 127;

    const int w = t >> 6;
    const int lane = t & 63;
    const int wt = w >> 2;              // token half (16 tokens)
    const int wk = w & 3;               // k quarter
    const int tok_t = lane >> 5;        // 2 groups x 8 tokens
    const int r_t = (lane >> 3) & 3;    // 4 groups x 8 r (2 f4)
    const int kl = lane & 7;            // 8-way k split
    const int kq = wk * 8 + kl;         // k-quad within tile [0,32)
    const int dwb = t & ~63;            // wave-uniform DMA dest base (f4)
    const int rsw0 = (r_t * 2 + 0) ^ kl;
    const int rsw1 = (r_t * 2 + 1) ^ kl;
    const int qoff = (wt * 16 + tok_t * 8) * 32 + kq;   // + j*32
    const int roff = kq * 32;                           // + kk*8 + rsw

    const float4* Qg4 = (const float4*)(Q + ((size_t)b * S_LEN + c32 * TMK) * D_DIM);
    const float4* Rg4 = (const float4*)(R + (size_t)b * D_DIM * NRR);

#define ISSUE(TILE, D)                                                        \
    {                                                                         \
        _Pragma("unroll")                                                     \
        for (int i = 0; i < 2; ++i) {                                         \
            const int f = t + 512 * i;          /* Q slot 0..1023 */          \
            __builtin_amdgcn_global_load_lds(                                 \
                (gas_t)(Qg4 + (size_t)(f >> 5) * 256 + (TILE) * 32 + (f & 31)),\
                (las_t)&smem4[(D) * 1024 + (i * 512) + dwb], 16, 0, 0);       \
        }                                                                     \
        _Pragma("unroll")                                                     \
        for (int i = 0; i < 2; ++i) {                                         \
            const int f = t + 512 * i;          /* R slot 0..1023 */          \
            __builtin_amdgcn_global_load_lds(                                 \
                (gas_t)(Rg4 + ((size_t)(TILE) * 128 + (f >> 3)) * 8           \
                        + ((f & 7) ^ ((f >> 5) & 7))),                        \
                (las_t)&smem4[2048 + (D) * 1024 + (i * 512) + dwb], 16, 0, 0);\
        }                                                                     \
    }

#define COMPUTE(D)                                                            \
    {                                                                         \
        const float4* qb = smem4 + (D) * 1024;                                \
        const float4* rb = smem4 + 2048 + (D) * 1024;                         \
        float4 rv[4][2];                                                      \
        _Pragma("unroll")                                                     \
        for (int kk = 0; kk < 4; ++kk) {                                      \
            rv[kk][0] = rb[roff + kk * 8 + rsw0];                             \
            rv[kk][1] = rb[roff + kk * 8 + rsw1];                             \
        }                                                                     \
        _Pragma("unroll")                                                     \
        for (int j = 0; j < 8; ++j) {                                         \
            const float4 qv = qb[qoff + j * 32];                              \
            _Pragma("unroll")                                                 \
            for (int kk = 0; kk < 4; ++kk) {                                  \
                const float s = kk == 0 ? qv.x : kk == 1 ? qv.y               \
                              : kk == 2 ? qv.z : qv.w;                        \
                _Pragma("unroll")                                             \
                for (int p = 0; p < 2; ++p) {                                 \
                    acc[j][p].x = fmaf(s, rv[kk][p].x, acc[j][p].x);          \
                    acc[j][p].y = fmaf(s, rv[kk][p].y, acc[j][p].y);          \
                    acc[j][p].z = fmaf(s, rv[kk][p].z, acc[j][p].z);          \
                    acc[j][p].w = fmaf(s, rv[kk][p].w, acc[j][p].w);          \
                }                                                             \
            }                                                                 \
        }                                                                     \
    }

    float4 acc[8][2];
#pragma unroll
    for (int j = 0; j < 8; ++j) {
        acc[j][0] = make_float4(0.f, 0.f, 0.f, 0.f);
        acc[j][1] = make_float4(0.f, 0.f, 0.f, 0.f);
    }
    if (t < NBK) cnt[t] = 0;

    ISSUE(0, 0)
    for (int tau = 0; tau < NT; ++tau) {
        if (tau + 1 < NT) {
            ISSUE(tau + 1, (tau + 1) & 1)
            // my tile-tau 4 DMAs landed; tau+1's 4 stay in flight
            asm volatile("s_waitcnt vmcnt(4)\n\ts_barrier" ::: "memory");
        } else {
            asm volatile("s_waitcnt vmcnt(0)\n\ts_barrier" ::: "memory");
        }
        COMPUTE(tau & 1)
        // all my LDS reads of this buffer done before DMA overwrites it
        asm volatile("s_waitcnt lgkmcnt(0)\n\ts_barrier" ::: "memory");
    }
#undef ISSUE
#undef COMPUTE

    // ---- reduce over kl (lane bits 0-2): lanes kl==0 hold wave partial ----
#pragma unroll
    for (int j = 0; j < 8; ++j)
#pragma unroll
        for (int p = 0; p < 2; ++p) {
#pragma unroll
            for (int off = 1; off < 8; off <<= 1) {
                acc[j][p].x += __shfl_xor(acc[j][p].x, off, 64);
                acc[j][p].y += __shfl_xor(acc[j][p].y, off, 64);
                acc[j][p].z += __shfl_xor(acc[j][p].z, off, 64);
                acc[j][p].w += __shfl_xor(acc[j][p].w, off, 64);
            }
        }
    __syncthreads();                    // main-loop LDS free for reuse

    // ---- dump 4 wk-slices [32 tok][8 rq f4] into smem4[0,1024) ----
    if (kl == 0) {
#pragma unroll
        for (int j = 0; j < 8; ++j) {
            const int tok = wt * 16 + tok_t * 8 + j;
            smem4[wk * 256 + tok * 8 + r_t * 2 + 0] = acc[j][0];
            smem4[wk * 256 + tok * 8 + r_t * 2 + 1] = acc[j][1];
        }
    }
    __syncthreads();

    // ---- sum 4 wk-slices (256 f4 positions) ----
    if (t < 256) {
        float4 s = smem4[t];
#pragma unroll
        for (int ww = 1; ww < 4; ++ww) {
            const float4 v = smem4[ww * 256 + t];
            s.x += v.x; s.y += v.y; s.z += v.z; s.w += v.w;
        }
        const int tok = t >> 3, rq = t & 7;
        xs[tok * 33 + rq * 4 + 0] = s.x;
        xs[tok * 33 + rq * 4 + 1] = s.y;
        xs[tok * 33 + rq * 4 + 2] = s.z;
        xs[tok * 33 + rq * 4 + 3] = s.w;
    }
    __syncthreads();

    if (t < TMK) {
        // argmax(concat[xR,-xR]) with first-occurrence tie-break
        float m1 = xs[t * 33 + 0]; int i1 = 0;
        float m2 = m1;             int i2 = 0;
#pragma unroll
        for (int r = 1; r < NRR; ++r) {
            const float v = xs[t * 33 + r];
            if (v > m1) { m1 = v; i1 = r; }
            if (v < m2) { m2 = v; i2 = r; }
        }
        const int bk = (m1 >= -m2) ? i1 : (NRR + i2);
        buckets[(size_t)b * S_LEN + c32 * TMK + t] = bk;
        atomicAdd(&cnt[bk], 1);
    }
    __syncthreads();
    if (t < NBK) hist[((size_t)b * NC32 + c32) * NBK + t] = cnt[t];
}

// One block, 256 threads: thread = (batch b = t/64, bucket bk = t%64).
__global__ __launch_bounds__(256) void k2_scan(
    const int* __restrict__ hist, int* __restrict__ chunkOffset)
{
    const int t = threadIdx.x;
    const int b = t >> 6;
    const int bk = t & 63;
    const int lane = t & 63;

    int total = 0;
    for (int c = 0; c < NC32; ++c)
        total += hist[((size_t)b * NC32 + c) * NBK + bk];

    int incl = total;
#pragma unroll
    for (int off = 1; off < 64; off <<= 1) {
        int n = __shfl_up(incl, off, 64);
        if (lane >= off) incl += n;
    }
    int run = incl - total;   // exclusive prefix over buckets = bucketStart

    for (int c = 0; c < NC32; ++c) {
        int h = hist[((size_t)b * NC32 + c) * NBK + bk];
        chunkOffset[((size_t)b * NC32 + c) * NBK + bk] = run;
        run += h;
    }
}

// Stable scatter: 32-token chunks; rank via ballot restricted to own 32-lane half.
__global__ __launch_bounds__(256) void k3_scatter(
    const int* __restrict__ buckets, const int* __restrict__ chunkOffset,
    int* __restrict__ out)
{
    const int gid = blockIdx.x * 256 + threadIdx.x;  // 0..16383
    const int b = gid >> 12;
    const int s = gid & (S_LEN - 1);
    const int chunk = s >> 5;                        // 32-token chunk
    const int lane = threadIdx.x & 63;

    const int bk = buckets[gid];

    unsigned long long m = ~0ull;
#pragma unroll
    for (int i = 0; i < 6; ++i) {
        unsigned long long bi = __ballot((bk >> i) & 1);
        m &= ((bk >> i) & 1) ? bi : ~bi;
    }
    const unsigned int m32 = (unsigned int)(m >> (lane & 32));
    const int rank = __popc(m32 & ((1u << (lane & 31)) - 1u));

    const int pos = chunkOffset[((size_t)b * NC32 + chunk) * NBK + bk] + rank;
    out[(size_t)b * S_LEN + pos] = s;
}

extern "C" void kernel_launch(void* const* d_in, const int* in_sizes, int n_in,
                              void* d_out, int out_size, void* d_ws, size_t ws_size,
                              hipStream_t stream) {
    const float* Q = (const float*)d_in[0];
    // d_in[1] = key, d_in[2] = value: dead code in the reference, never read.
    const float* R = (const float*)d_in[3];

    int* buckets     = (int*)d_ws;                      // 16384 ints
    int* hist        = buckets + B_DIM * S_LEN;         // 4*128*64 = 32768 ints
    int* chunkOffset = hist + B_DIM * NC32 * NBK;       // 32768 ints

    k1_buckets<<<B_DIM * NC32, 512, 0, stream>>>(Q, R, buckets, hist);
    k2_scan   <<<1,            256, 0, stream>>>(hist, chunkOffset);
    k3_scatter<<<(B_DIM * S_LEN) / 256, 256, 0, stream>>>(buckets, chunkOffset, (int*)d_out);
}